// Round 12
// baseline (242.236 us; speedup 1.0000x reference)
//
#include <hip/hip_runtime.h>
#include <math.h>

// ---------------------------------------------------------------------------
// EMD layer (Sinkhorn-OT logits) for MI355X.
// support: [32,512,8,8] f32, query: [256,512,8,8] f32 -> logits [256,32] f32.
//
// R12: marg_kernel folded into emd via the centering identity
//      <U_raw[:,n], V_raw[:,j]> = nrm_un*nrm_vj*sim[n][j] + 512*mu_un*mu_vj
//      (cross terms vanish: <Un,1>=0). So
//      a_raw[n] = (1/64)*nrm_un*sum_j nrm_vj*sim[n][j] + mu_un*Ssc_w
//      b_raw[n] = (1/64)*nrm_vn*sum_i nrm_ui*sim[i][n] + mu_vn*Ssc_q
//      -- one extra weighted matvec + reduce in the layout emd already has.
//      marg deleted; norm drops pool/BpT/QpT; 2 launches total.
// ---------------------------------------------------------------------------

#define DEV static __device__ __forceinline__

typedef _Float16 half8 __attribute__((ext_vector_type(8)));
typedef float floatx4 __attribute__((ext_vector_type(4)));

DEV float fast_rcp(float x) {
#if __has_builtin(__builtin_amdgcn_rcpf)
    return __builtin_amdgcn_rcpf(x);
#else
    return 1.0f / x;
#endif
}
DEV float fexp2(float x) {
#if __has_builtin(__builtin_amdgcn_exp2f)
    return __builtin_amdgcn_exp2f(x);
#else
    return exp2f(x);
#endif
}
DEV float flog2(float x) {
#if __has_builtin(__builtin_amdgcn_logf)
    return __builtin_amdgcn_logf(x);
#else
    return log2f(x);
#endif
}

#define K_SIM2M 28.853900817779268f    // 20/ln2 : M = 2^((sim-1)*K_SIM2M)
#define K_M2SIM 0.034657359027997264f  // 0.05*ln2 : sim = 1 + log2(M)*K_M2SIM
#define LDP 68                         // padded LDS row stride (floats)

// ------ K1: center+normalize over C -> fp16 FRAGMENT order, + stats ---------
// 1024 threads: 16 waves. Fragment chunk (kk,t,slot) = channels
// kk*32+(slot>>4)*8..+8 of node t*16+(slot&15), at ((kk*4+t)*64+slot)*8 halves.
__global__ void __launch_bounds__(1024, 1)
norm_kernel(const float* __restrict__ support, const float* __restrict__ query,
            _Float16* __restrict__ Vht, _Float16* __restrict__ Uht,
            float* __restrict__ muA, float* __restrict__ nrmA,
            float* __restrict__ Ssc) {
    __shared__ float red1[16][64];
    __shared__ float red2[16][64];
    __shared__ float muL[64], invL[64];
    __shared__ float tile[128][65];

    int sid = blockIdx.x;             // 0..287
    const float* src;
    _Float16* dst;
    if (sid < 32) {
        src = support + (size_t)sid * 32768; dst = Vht + (size_t)sid * 32768;
    } else {
        src = query + (size_t)(sid - 32) * 32768; dst = Uht + (size_t)(sid - 32) * 32768;
    }

    int node = threadIdx.x & 63;
    int cq   = threadIdx.x >> 6;      // wave index 0..15

    // ---- stats pass: each wave handles 32 channels ----
    float s1 = 0.f, s2 = 0.f;
#pragma unroll 8
    for (int j = 0; j < 32; ++j) {
        int c = cq * 32 + j;
        float x = src[c * 64 + node];
        s1 += x; s2 += x * x;
    }
    red1[cq][node] = s1;
    red2[cq][node] = s2;
    __syncthreads();
    if (threadIdx.x < 64) {
        float t1 = 0.f, t2 = 0.f;
#pragma unroll
        for (int k = 0; k < 16; ++k) { t1 += red1[k][node]; t2 += red2[k][node]; }
        float mu  = t1 * (1.0f / 512.0f);
        float ss  = t2 - 512.0f * mu * mu;
        float nrm = fmaxf(sqrtf(fmaxf(ss, 0.0f)), 1e-8f);
        muL[node]  = mu;
        invL[node] = 1.0f / nrm;
        muA[sid * 64 + node]  = mu;
        nrmA[sid * 64 + node] = nrm;
        float sS = t1;                 // Ssc = (1/64) * total sum = sum_c pool[c]
        sS += __shfl_xor(sS, 1);  sS += __shfl_xor(sS, 2);  sS += __shfl_xor(sS, 4);
        sS += __shfl_xor(sS, 8);  sS += __shfl_xor(sS, 16); sS += __shfl_xor(sS, 32);
        if (node == 0) Ssc[sid] = sS * (1.0f / 64.0f);
    }
    __syncthreads();

    // ---- normalize + fragment-order write, slab = 128 channels ----
    float mu = muL[node], inv = invL[node];
    for (int ch = 0; ch < 4; ++ch) {
#pragma unroll
        for (int j = 0; j < 8; ++j) {
            int cl = cq * 8 + j;       // 16 waves x 8 = 128 channels
            float x = src[(ch * 128 + cl) * 64 + node];
            tile[cl][node] = (x - mu) * inv;
        }
        __syncthreads();
        // 1024 fragment chunks per slab: exactly one per thread
        {
            int g    = threadIdx.x;    // kkl*256 + t*64 + slot
            int slot = g & 63;
            int t    = (g >> 6) & 3;
            int kkl  = g >> 8;
            int nd   = t * 16 + (slot & 15);
            int c8   = (kkl << 2) | (slot >> 4);
            half8 v;
#pragma unroll
            for (int i = 0; i < 8; ++i) v[i] = (_Float16)tile[c8 * 8 + i][nd];
            *(half8*)(dst + ((size_t)ch * 1024 + g) * 8) = v;
        }
        __syncthreads();
    }
}

// --------- K2: FUSED sim + marginals + exp/transpose + Sinkhorn + logits ----
// Wave per (q,w). XCD-resident: blockIdx%8 = XCD handles one q-group.
// Permuted layout: slot s of lane (ig,jg) = col jg*8+(ig^s); slot t = row
// ig*8+(jg^t). Lane owns row ig*8+jg (t=0) and col jg*8+ig (s=0).
__global__ void __launch_bounds__(256, 4)
emd_kernel(const _Float16* __restrict__ Uht, const _Float16* __restrict__ Vht,
           const float* __restrict__ muA, const float* __restrict__ nrmA,
           const float* __restrict__ Ssc, float* __restrict__ out) {
    __shared__ __align__(16) float T[2][64 * LDP];   // 34.8 KB

    int x    = blockIdx.x & 7;
    int i    = blockIdx.x >> 3;
    int w    = i & 31;
    int wave = threadIdx.x >> 6;
    int lane = threadIdx.x & 63;
    int q    = (x * 8 + (i >> 5)) * 4 + wave;        // XCD x: q in [32x,32x+32)
    int lo16 = lane & 15;
    int hi4  = lane >> 4;
    int ig   = lane >> 3;
    int jg   = lane & 7;

    // ---- phase 1: sim tile via fp16 MFMA, fragment-order loads ----
    floatx4 acc[4][4];
#pragma unroll
    for (int tm = 0; tm < 4; ++tm)
#pragma unroll
        for (int tn = 0; tn < 4; ++tn)
            acc[tm][tn] = (floatx4){0.f, 0.f, 0.f, 0.f};

    const _Float16* Abase = Uht + (size_t)q * 32768 + lane * 8;
    const _Float16* Bbase = Vht + (size_t)w * 32768 + lane * 8;
#pragma unroll 1
    for (int kk = 0; kk < 16; ++kk) {
        half8 bf[4];
#pragma unroll
        for (int t = 0; t < 4; ++t)
            bf[t] = *(const half8*)(Bbase + (size_t)(kk * 4 + t) * 512);
#pragma unroll
        for (int tm = 0; tm < 4; ++tm) {
            half8 af = *(const half8*)(Abase + (size_t)(kk * 4 + tm) * 512);
#pragma unroll
            for (int tn = 0; tn < 4; ++tn)
                acc[tm][tn] = __builtin_amdgcn_mfma_f32_16x16x32_f16(
                    af, bf[tn], acc[tm][tn], 0, 0, 0);
        }
    }

    // ---- wave-uniform tile max for the fp16 rescale ----
    float lmax = -2.0f;
#pragma unroll
    for (int tm = 0; tm < 4; ++tm)
#pragma unroll
        for (int tn = 0; tn < 4; ++tn)
#pragma unroll
            for (int r = 0; r < 4; ++r) lmax = fmaxf(lmax, acc[tm][tn][r]);
    lmax = fmaxf(lmax, __shfl_xor(lmax, 1));
    lmax = fmaxf(lmax, __shfl_xor(lmax, 2));
    lmax = fmaxf(lmax, __shfl_xor(lmax, 4));
    lmax = fmaxf(lmax, __shfl_xor(lmax, 8));
    lmax = fmaxf(lmax, __shfl_xor(lmax, 16));
    lmax = fmaxf(lmax, __shfl_xor(lmax, 32));
    float s0 = lmax;

    // ---- marginal weights (permuted gathers; w wave-uniform, q per-wave) ----
    float nw[8], nu[8];
#pragma unroll
    for (int s = 0; s < 8; ++s) nw[s] = nrmA[w * 64 + (jg * 8 + (ig ^ s))];
#pragma unroll
    for (int t = 0; t < 8; ++t) nu[t] = nrmA[(32 + q) * 64 + (ig * 8 + (jg ^ t))];
    float muR = muA[(32 + q) * 64 + (ig * 8 + jg)];   // own row node (query)
    float muC = muA[w * 64 + (jg * 8 + ig)];          // own col node (support)
    float Sw  = Ssc[w];
    float Sq  = Ssc[32 + q];

    // ---- phase 2: LDS roundtrip of raw sim into xor-permuted layout;
    //      on read: weighted matvecs (marginals) + exp -> fp16 Mh ----
    half8 Mh[8];
    float pa[8], cb[8];
#pragma unroll
    for (int s = 0; s < 8; ++s) cb[s] = 0.f;
#pragma unroll 1
    for (int round = 0; round < 2; ++round) {
        if ((wave >> 1) == round) {
            float* buf = T[wave & 1];
#pragma unroll
            for (int tm = 0; tm < 4; ++tm)
#pragma unroll
                for (int tn = 0; tn < 4; ++tn)
#pragma unroll
                    for (int r = 0; r < 4; ++r) {
                        int row = tm * 16 + hi4 * 4 + r;
                        int col = tn * 16 + lo16;
                        int sp  = (col & 7) ^ (row >> 3);
                        buf[row * LDP + (col & ~7) + sp] = acc[tm][tn][r];
                    }
        }
        __syncthreads();
        if ((wave >> 1) == round) {
            const float* buf = T[wave & 1];
#pragma unroll
            for (int t = 0; t < 8; ++t) {
                const float* p = buf + (ig * 8 + (jg ^ t)) * LDP + jg * 8;
                float4 m0 = *(const float4*)p;
                float4 m1 = *(const float4*)(p + 4);
                float mm[8] = {m0.x, m0.y, m0.z, m0.w, m1.x, m1.y, m1.z, m1.w};
                float s = mm[0] * nw[0];
#pragma unroll
                for (int c = 1; c < 8; ++c) s = fmaf(mm[c], nw[c], s);
                pa[t] = s;
#pragma unroll
                for (int c = 0; c < 8; ++c) cb[c] = fmaf(mm[c], nu[t], cb[c]);
                half8 h;
#pragma unroll
                for (int c = 0; c < 8; ++c)
                    h[c] = (_Float16)fexp2((mm[c] - s0) * K_SIM2M);
                Mh[t] = h;
            }
        }
        __syncthreads();
    }

    // ---- marginals: reduce-scatter weighted sums, relu+eps, normalize ----
    pa[0] += __shfl_xor(pa[4], 4); pa[1] += __shfl_xor(pa[5], 4);
    pa[2] += __shfl_xor(pa[6], 4); pa[3] += __shfl_xor(pa[7], 4);
    pa[0] += __shfl_xor(pa[2], 2); pa[1] += __shfl_xor(pa[3], 2);
    pa[0] += __shfl_xor(pa[1], 1);         // sum_j nrm_vj * sim[row_own][j]
    cb[0] += __shfl_xor(cb[4], 32); cb[1] += __shfl_xor(cb[5], 32);
    cb[2] += __shfl_xor(cb[6], 32); cb[3] += __shfl_xor(cb[7], 32);
    cb[0] += __shfl_xor(cb[2], 16); cb[1] += __shfl_xor(cb[3], 16);
    cb[0] += __shfl_xor(cb[1], 8);         // sum_i nrm_ui * sim[i][col_own]

    float araw = fmaf(muR, Sw, nu[0] * pa[0] * 0.015625f);
    float braw = fmaf(muC, Sq, nw[0] * cb[0] * 0.015625f);

    float va = fmaxf(araw, 0.0f) + 0.001f;  va += 1e-5f;
    float sa = va;
    sa += __shfl_xor(sa, 1);  sa += __shfl_xor(sa, 2);  sa += __shfl_xor(sa, 4);
    sa += __shfl_xor(sa, 8);  sa += __shfl_xor(sa, 16); sa += __shfl_xor(sa, 32);
    float a_own = va * (64.0f / sa);

    float vb = fmaxf(braw, 0.0f) + 0.001f;  vb += 1e-5f;
    float sb = vb;
    sb += __shfl_xor(sb, 1);  sb += __shfl_xor(sb, 2);  sb += __shfl_xor(sb, 4);
    sb += __shfl_xor(sb, 8);  sb += __shfl_xor(sb, 16); sb += __shfl_xor(sb, 32);
    float b_own = vb * (64.0f / sb);

    // ---- phase 3: Sinkhorn, reduce-scatter + all-gather, tol early exit ----
    float wvp[8];
#pragma unroll
    for (int s = 0; s < 8; ++s) wvp[s] = 1.0f;
    float q8[8];
    float w_prev = -1.f;

#pragma unroll 1
    for (int it = 0; it < 100; ++it) {
        float p[8];
#pragma unroll
        for (int t = 0; t < 8; ++t) {
            float s = (float)Mh[t][0] * wvp[0];
#pragma unroll
            for (int c = 1; c < 8; ++c) s = fmaf((float)Mh[t][c], wvp[c], s);
            p[t] = s;
        }
        p[0] += __shfl_xor(p[4], 4); p[1] += __shfl_xor(p[5], 4);
        p[2] += __shfl_xor(p[6], 4); p[3] += __shfl_xor(p[7], 4);
        p[0] += __shfl_xor(p[2], 2); p[1] += __shfl_xor(p[3], 2);
        p[0] += __shfl_xor(p[1], 1);
        float z_own = a_own * fast_rcp(p[0]);
        q8[0] = z_own;
        q8[1] = __shfl_xor(q8[0], 1);
        q8[2] = __shfl_xor(q8[0], 2); q8[3] = __shfl_xor(q8[1], 2);
        q8[4] = __shfl_xor(q8[0], 4); q8[5] = __shfl_xor(q8[1], 4);
        q8[6] = __shfl_xor(q8[2], 4); q8[7] = __shfl_xor(q8[3], 4);
        float cp[8];
#pragma unroll
        for (int s = 0; s < 8; ++s) {
            float v = (float)Mh[0][s] * q8[0];
#pragma unroll
            for (int t = 1; t < 8; ++t) v = fmaf((float)Mh[t][s], q8[t], v);
            cp[s] = v;
        }
        cp[0] += __shfl_xor(cp[4], 32); cp[1] += __shfl_xor(cp[5], 32);
        cp[2] += __shfl_xor(cp[6], 32); cp[3] += __shfl_xor(cp[7], 32);
        cp[0] += __shfl_xor(cp[2], 16); cp[1] += __shfl_xor(cp[3], 16);
        cp[0] += __shfl_xor(cp[1], 8);
        float w_own = b_own * fast_rcp(cp[0]);
        wvp[0] = w_own;
        wvp[1] = __shfl_xor(wvp[0], 8);
        wvp[2] = __shfl_xor(wvp[0], 16); wvp[3] = __shfl_xor(wvp[1], 16);
        wvp[4] = __shfl_xor(wvp[0], 32); wvp[5] = __shfl_xor(wvp[1], 32);
        wvp[6] = __shfl_xor(wvp[2], 32); wvp[7] = __shfl_xor(wvp[3], 32);
        // w stable across all 64 cols -> next z,w identical -> fixed point
        bool same = fabsf(w_own - w_prev) <= 1e-5f * w_own;
        w_prev = w_own;
        if (__all(same)) break;
    }

    // ---- phase 4: logits; sim = s0 + log2(M')*eps*ln2 ----
    float s = 0.f;
#pragma unroll
    for (int t = 0; t < 8; ++t)
#pragma unroll
        for (int c = 0; c < 8; ++c) {
            float m    = fmaxf((float)Mh[t][c], 1e-30f);
            float sim  = fmaf(flog2(m), K_M2SIM, s0);
            float flow = q8[t] * m * wvp[c];
            s = fmaf(sim, flow, s);
        }
    s += __shfl_xor(s, 1);  s += __shfl_xor(s, 2);  s += __shfl_xor(s, 4);
    s += __shfl_xor(s, 8);  s += __shfl_xor(s, 16); s += __shfl_xor(s, 32);
    if (lane == 0) out[q * 32 + w] = s * 0.1953125f;   // 12.5/64
}

// ---------------------------------------------------------------------------
extern "C" void kernel_launch(void* const* d_in, const int* in_sizes, int n_in,
                              void* d_out, int out_size, void* d_ws, size_t ws_size,
                              hipStream_t stream) {
    (void)in_sizes; (void)n_in; (void)out_size; (void)ws_size;
    const float* support = (const float*)d_in[0];   // 32*512*64
    const float* query   = (const float*)d_in[1];   // 256*512*64

    char* ws = (char*)d_ws;
    _Float16* Uht = (_Float16*)ws;                  // 16 MB (fragment order)
    _Float16* Vht = Uht + 8388608;                  //  2 MB (fragment order)
    float* muA  = (float*)(Vht + 1048576);          // 72 KB [288][64]
    float* nrmA = muA + 18432;                      // 72 KB
    float* Ssc  = nrmA + 18432;                     // ~1 KB [288]  (~18.2 MB)

    norm_kernel<<<288, 1024, 0, stream>>>(support, query, Vht, Uht,
                                          muA, nrmA, Ssc);
    emd_kernel<<<2048, 256, 0, stream>>>(Uht, Vht, muA, nrmA, Ssc,
                                         (float*)d_out);
}